// Round 2
// baseline (28719.153 us; speedup 1.0000x reference)
//
#include <hip/hip_runtime.h>

// HeteroGNN (2-layer bipartite SAGE-Hybrid).
// Per direction: scatter-sum -> single split-bf16 MFMA GEMM with K-concat
// A' = [s | s/cnt | x] (K=1536, interleaved per 32-step) x B' (pre-stacked,
// pre-split hi/lo bf16) -> LN+ReLU.
// out = s@Wl0^T + (s/max(cnt,1))@Wl1^T + x_dst@(Wr0+Wr1)^T + (bl0+bl1)

typedef float f4 __attribute__((ext_vector_type(4)));
typedef short short8 __attribute__((ext_vector_type(8)));

#define C 512
#define CC (512*512)
#define NST 48          // K-steps: 1536 / 32
#define BSTEP 16384     // 512*32 elements per (step,plane) B panel

// fp32 -> (hi, lo) bf16 split, both RNE. x == hi + lo up to ~2^-17 rel.
__device__ __forceinline__ void bf16split(float x, short& h, short& l) {
    unsigned u = __float_as_uint(x);
    unsigned hb = (u + 0x7FFFu + ((u >> 16) & 1u)) & 0xFFFF0000u;
    h = (short)(hb >> 16);
    float r = x - __uint_as_float(hb);
    unsigned ur = __float_as_uint(r);
    l = (short)((ur + 0x7FFFu + ((ur >> 16) & 1u)) >> 16);
}

// ---------------- weight prep ----------------
// Build B' bf16 hi/lo panels per direction d=(l*2+e):
// logical B'[k'][n], k' interleaved in triples of 32: step 3t+j covers rows
// 32t..32t+31 of {Wl0^T (j=0), Wl1^T (j=1), (Wr0+Wr1)^T (j=2)}.
// Bp layout: [(d*NST + step)*2 + plane][n=512][k=32] bf16.
__global__ __launch_bounds__(256) void prep_b_kernel(
    const float* __restrict__ Wl, const float* __restrict__ Wr,
    unsigned short* __restrict__ Bp)
{
    int nrow = blockIdx.x;                  // output col n (0..511)
    int z = blockIdx.y;                     // d*3 + j
    int d = z / 3, j = z - d * 3;
    const float* s0 = (j < 2) ? Wl + (size_t)(d * 2 + j) * CC
                              : Wr + (size_t)(d * 2 + 0) * CC;
    const float* s1 = (j == 2) ? Wr + (size_t)(d * 2 + 1) * CC : nullptr;
    int t = threadIdx.x;
    #pragma unroll
    for (int c = 0; c < 2; ++c) {
        int kk = t + c * 256;               // source k (0..511), coalesced
        float v = s0[(size_t)nrow * C + kk];
        if (s1) v += s1[(size_t)nrow * C + kk];
        short hh, ll;
        bf16split(v, hh, ll);
        int st = 3 * (kk >> 5) + j;
        int k = kk & 31;
        size_t base = (size_t)(d * NST + st) * 2 * BSTEP + (size_t)nrow * 32 + k;
        Bp[base] = (unsigned short)hh;
        Bp[base + BSTEP] = (unsigned short)ll;
    }
}

// ---------------- scatter: s[dst] += X[src], cnt[dst] += 1 ----------------
__global__ __launch_bounds__(256) void scatter_kernel(
    const float* __restrict__ X, const int* __restrict__ src, const int* __restrict__ dst,
    float* __restrict__ S, float* __restrict__ cnt, int E)
{
    int e = blockIdx.x * 4 + (threadIdx.x >> 6);
    if (e >= E) return;
    int lane = threadIdx.x & 63;
    int si = src[e], di = dst[e];
    const f4* xr = (const f4*)(X + (size_t)si * C) + lane * 2;
    f4 v0 = xr[0], v1 = xr[1];
    float* sp = S + (size_t)di * C + lane * 8;
    unsafeAtomicAdd(sp + 0, v0[0]); unsafeAtomicAdd(sp + 1, v0[1]);
    unsafeAtomicAdd(sp + 2, v0[2]); unsafeAtomicAdd(sp + 3, v0[3]);
    unsafeAtomicAdd(sp + 4, v1[0]); unsafeAtomicAdd(sp + 5, v1[1]);
    unsafeAtomicAdd(sp + 6, v1[2]); unsafeAtomicAdd(sp + 7, v1[3]);
    if (lane == 0) unsafeAtomicAdd(cnt + di, 1.0f);
}

// ---------------- split-bf16 MFMA GEMM ----------------
// Out[r][n] = sum_k' A'[r][k'] B'[k'][n] + bias0[n] + bias1[n]
// A' staged per 32-step from global fp32 (s / s*ic / x per step%3), split to
// hi/lo bf16 in LDS. Tile 128x128, 4 waves (2x2), wave tile 64x64 (4x4 frags
// of 16x16), mfma_f32_16x16x32_bf16, 3 products per frag-step (drop lo*lo).
__global__ __launch_bounds__(256) void gemm_mfma_kernel(
    const float* __restrict__ S, const float* __restrict__ Xd,
    const unsigned short* __restrict__ BpD,     // this direction's panels
    const float* __restrict__ bias0, const float* __restrict__ bias1,
    const float* __restrict__ cnt, float* __restrict__ Out, int n)
{
    __shared__ __align__(16) unsigned short Ah[128][40];
    __shared__ __align__(16) unsigned short Al[128][40];
    __shared__ __align__(16) unsigned short Bh[128][40];
    __shared__ __align__(16) unsigned short Bl[128][40];

    int t = threadIdx.x;
    int row0 = blockIdx.x * 128, col0 = blockIdx.y * 128;
    int wid = t >> 6, l = t & 63;
    int wm = wid >> 1, wn = wid & 1;
    int ln = l & 15, kg = l >> 4;

    // A staging: thread t -> row ar, k-half akh (16 of 32)
    int ar = t >> 1, akh = (t & 1) * 16;
    int rc = row0 + ar; if (rc > n - 1) rc = n - 1;       // clamp (invalid rows harmless)
    float ic = 1.0f / fmaxf(cnt[rc], 1.0f);
    const float* Sp = S + (size_t)rc * C;
    const float* Xp = Xd + (size_t)rc * C;
    // B staging: thread t -> local col t>>2 (+64), k-offset (t&3)*8
    int bnr = t >> 2, bko = (t & 3) * 8;

    f4 acc[4][4];
    #pragma unroll
    for (int i = 0; i < 4; ++i)
        #pragma unroll
        for (int jj = 0; jj < 4; ++jj) acc[i][jj] = (f4)0.0f;

    f4 pa[4];
    short8 pb0[2], pb1[2];
    int gcur;

    // prologue: load step 0
    {
        const float* ab = Sp + akh;           // st=0 -> kt=0, g=0 -> S
        pa[0] = *(const f4*)ab; pa[1] = *(const f4*)(ab + 4);
        pa[2] = *(const f4*)(ab + 8); pa[3] = *(const f4*)(ab + 12);
        const unsigned short* bp = BpD + (size_t)(col0 + bnr) * 32 + bko;
        pb0[0] = *(const short8*)bp;
        pb0[1] = *(const short8*)(bp + 64 * 32);
        pb1[0] = *(const short8*)(bp + BSTEP);
        pb1[1] = *(const short8*)(bp + BSTEP + 64 * 32);
        gcur = 0;
    }

    for (int st = 0; st < NST; ++st) {
        __syncthreads();
        // ---- write staged regs to LDS (split A to hi/lo) ----
        {
            float sc = (gcur == 1) ? ic : 1.0f;
            short8 h0, l0, h1, l1;
            #pragma unroll
            for (int q = 0; q < 2; ++q)
                #pragma unroll
                for (int jj = 0; jj < 4; ++jj) {
                    short hh, ll;
                    bf16split(pa[q][jj] * sc, hh, ll);
                    h0[q * 4 + jj] = hh; l0[q * 4 + jj] = ll;
                }
            #pragma unroll
            for (int q = 0; q < 2; ++q)
                #pragma unroll
                for (int jj = 0; jj < 4; ++jj) {
                    short hh, ll;
                    bf16split(pa[q + 2][jj] * sc, hh, ll);
                    h1[q * 4 + jj] = hh; l1[q * 4 + jj] = ll;
                }
            *(short8*)&Ah[ar][akh] = h0; *(short8*)&Ah[ar][akh + 8] = h1;
            *(short8*)&Al[ar][akh] = l0; *(short8*)&Al[ar][akh + 8] = l1;
            *(short8*)&Bh[bnr][bko] = pb0[0]; *(short8*)&Bh[bnr + 64][bko] = pb0[1];
            *(short8*)&Bl[bnr][bko] = pb1[0]; *(short8*)&Bl[bnr + 64][bko] = pb1[1];
        }
        __syncthreads();
        // ---- prefetch step st+1 into regs (overlaps with MFMAs below) ----
        if (st + 1 < NST) {
            int stn = st + 1;
            int kt = stn / 3, g = stn - kt * 3;
            const float* ab = (g == 2 ? Xp : Sp) + kt * 32 + akh;
            pa[0] = *(const f4*)ab; pa[1] = *(const f4*)(ab + 4);
            pa[2] = *(const f4*)(ab + 8); pa[3] = *(const f4*)(ab + 12);
            const unsigned short* bp = BpD + (size_t)(stn * 2) * BSTEP
                                     + (size_t)(col0 + bnr) * 32 + bko;
            pb0[0] = *(const short8*)bp;
            pb0[1] = *(const short8*)(bp + 64 * 32);
            pb1[0] = *(const short8*)(bp + BSTEP);
            pb1[1] = *(const short8*)(bp + BSTEP + 64 * 32);
            gcur = g;
        }
        // ---- compute: 16 frags x 3 split-products ----
        {
            short8 fbh[4], fbl[4];
            #pragma unroll
            for (int nf = 0; nf < 4; ++nf) {
                fbh[nf] = *(const short8*)&Bh[wn * 64 + nf * 16 + ln][kg * 8];
                fbl[nf] = *(const short8*)&Bl[wn * 64 + nf * 16 + ln][kg * 8];
            }
            #pragma unroll
            for (int mf = 0; mf < 4; ++mf) {
                short8 fah = *(const short8*)&Ah[wm * 64 + mf * 16 + ln][kg * 8];
                short8 fal = *(const short8*)&Al[wm * 64 + mf * 16 + ln][kg * 8];
                #pragma unroll
                for (int nf = 0; nf < 4; ++nf) {
                    acc[mf][nf] = __builtin_amdgcn_mfma_f32_16x16x32_bf16(
                        fah, fbh[nf], acc[mf][nf], 0, 0, 0);
                    acc[mf][nf] = __builtin_amdgcn_mfma_f32_16x16x32_bf16(
                        fah, fbl[nf], acc[mf][nf], 0, 0, 0);
                    acc[mf][nf] = __builtin_amdgcn_mfma_f32_16x16x32_bf16(
                        fal, fbh[nf], acc[mf][nf], 0, 0, 0);
                }
            }
        }
    }

    // ---- epilogue: bias + store (C/D: col = lane&15, row = (lane>>4)*4+reg) ----
    float bv[4];
    #pragma unroll
    for (int nf = 0; nf < 4; ++nf) {
        int cc = col0 + wn * 64 + nf * 16 + ln;
        bv[nf] = bias0[cc] + bias1[cc];
    }
    #pragma unroll
    for (int mf = 0; mf < 4; ++mf) {
        int rbase = row0 + wm * 64 + mf * 16 + kg * 4;
        #pragma unroll
        for (int jj = 0; jj < 4; ++jj) {
            int row = rbase + jj;
            if (row < n) {
                #pragma unroll
                for (int nf = 0; nf < 4; ++nf)
                    Out[(size_t)row * C + col0 + wn * 64 + nf * 16 + ln] =
                        acc[mf][nf][jj] + bv[nf];
            }
        }
    }
}

// ---------------- LayerNorm + ReLU (wave per row, matches jnp.var) ----------------
__global__ __launch_bounds__(256) void ln_relu_kernel(
    const float* __restrict__ In, float* __restrict__ Out,
    const float* __restrict__ g, const float* __restrict__ b, int N)
{
    int row = blockIdx.x * 4 + (threadIdx.x >> 6);
    if (row >= N) return;
    int lane = threadIdx.x & 63;
    const float* ip = In + (size_t)row * C + lane * 8;
    f4 v0 = *(const f4*)ip;
    f4 v1 = *(const f4*)(ip + 4);
    float s = v0[0] + v0[1] + v0[2] + v0[3] + v1[0] + v1[1] + v1[2] + v1[3];
    #pragma unroll
    for (int off = 32; off > 0; off >>= 1) s += __shfl_xor(s, off, 64);
    float mu = s * (1.0f / 512.0f);
    f4 e0 = v0 - mu, e1 = v1 - mu;
    float q = e0[0]*e0[0] + e0[1]*e0[1] + e0[2]*e0[2] + e0[3]*e0[3]
            + e1[0]*e1[0] + e1[1]*e1[1] + e1[2]*e1[2] + e1[3]*e1[3];
    #pragma unroll
    for (int off = 32; off > 0; off >>= 1) q += __shfl_xor(q, off, 64);
    float rs = rsqrtf(q * (1.0f / 512.0f) + 1e-5f);
    const float* gp = g + lane * 8;
    const float* bp = b + lane * 8;
    f4 g0 = *(const f4*)gp, g1 = *(const f4*)(gp + 4);
    f4 bb0 = *(const f4*)bp, bb1 = *(const f4*)(bp + 4);
    f4 o0 = g0 * (e0 * rs) + bb0;
    f4 o1 = g1 * (e1 * rs) + bb1;
    #pragma unroll
    for (int jj = 0; jj < 4; ++jj) { o0[jj] = fmaxf(o0[jj], 0.0f); o1[jj] = fmaxf(o1[jj], 0.0f); }
    float* op = Out + (size_t)row * C + lane * 8;
    *(f4*)op = o0;
    *(f4*)(op + 4) = o1;
}

extern "C" void kernel_launch(void* const* d_in, const int* in_sizes, int n_in,
                              void* d_out, int out_size, void* d_ws, size_t ws_size,
                              hipStream_t stream)
{
    (void)n_in; (void)out_size; (void)ws_size;
    const float* x_user = (const float*)d_in[0];
    const float* x_item = (const float*)d_in[1];
    const float* Wl     = (const float*)d_in[2];
    const float* bl     = (const float*)d_in[3];
    const float* Wr     = (const float*)d_in[4];
    const float* ln_g   = (const float*)d_in[5];
    const float* ln_b   = (const float*)d_in[6];
    const int* edge_ui  = (const int*)d_in[7];
    const int* edge_iu  = (const int*)d_in[8];

    int Nu = in_sizes[0] / C;
    int Ni = in_sizes[1] / C;
    int E  = in_sizes[7] / 2;
    int Nmax = Nu > Ni ? Nu : Ni;

    float* out_u = (float*)d_out;
    float* out_i = out_u + (size_t)Nu * C;

    // ws: Bp (6.29M ushort = 12.6MB) | sbuf (Nmax*C f32) | cnt | tmp (Nmax*C f32)
    unsigned short* Bp = (unsigned short*)d_ws;
    float* sbuf = (float*)(Bp + (size_t)4 * NST * 2 * BSTEP);
    float* cnt  = sbuf + (size_t)Nmax * C;
    float* tmp  = cnt + (size_t)((Nmax + 63) & ~63);
    size_t zero_bytes = ((size_t)Nmax * C + (size_t)Nmax) * sizeof(float);
    size_t dstride = (size_t)NST * 2 * BSTEP;   // Bp per-direction stride

    prep_b_kernel<<<dim3(512, 12), 256, 0, stream>>>(Wl, Wr, Bp);

    dim3 gscat((E + 3) / 4);
    dim3 ggemm_i((Ni + 127) / 128, 4), ggemm_u((Nu + 127) / 128, 4);
    int lnb_i = (Ni + 3) / 4, lnb_u = (Nu + 3) / 4;

    // -------- layer 1 --------
    hipMemsetAsync(sbuf, 0, zero_bytes, stream);
    scatter_kernel<<<gscat, 256, 0, stream>>>(x_user, edge_ui, edge_ui + E, sbuf, cnt, E);
    gemm_mfma_kernel<<<ggemm_i, 256, 0, stream>>>(sbuf, x_item, Bp + 0 * dstride,
                                                  bl + 0 * C, bl + 1 * C, cnt, out_i, Ni);
    hipMemsetAsync(sbuf, 0, zero_bytes, stream);
    scatter_kernel<<<gscat, 256, 0, stream>>>(x_item, edge_iu, edge_iu + E, sbuf, cnt, E);
    gemm_mfma_kernel<<<ggemm_u, 256, 0, stream>>>(sbuf, x_user, Bp + 1 * dstride,
                                                  bl + 2 * C, bl + 3 * C, cnt, out_u, Nu);
    ln_relu_kernel<<<lnb_u, 256, 0, stream>>>(out_u, out_u, ln_g + 0 * C, ln_b + 0 * C, Nu);
    ln_relu_kernel<<<lnb_i, 256, 0, stream>>>(out_i, out_i, ln_g + 1 * C, ln_b + 1 * C, Ni);

    // -------- layer 2 --------
    hipMemsetAsync(sbuf, 0, zero_bytes, stream);
    scatter_kernel<<<gscat, 256, 0, stream>>>(out_u, edge_ui, edge_ui + E, sbuf, cnt, E);
    gemm_mfma_kernel<<<ggemm_i, 256, 0, stream>>>(sbuf, out_i, Bp + 2 * dstride,
                                                  bl + 4 * C, bl + 5 * C, cnt, tmp, Ni);
    hipMemsetAsync(sbuf, 0, zero_bytes, stream);
    scatter_kernel<<<gscat, 256, 0, stream>>>(out_i, edge_iu, edge_iu + E, sbuf, cnt, E);
    ln_relu_kernel<<<lnb_i, 256, 0, stream>>>(tmp, out_i, ln_g + 3 * C, ln_b + 3 * C, Ni);
    gemm_mfma_kernel<<<ggemm_u, 256, 0, stream>>>(sbuf, out_u, Bp + 3 * dstride,
                                                  bl + 6 * C, bl + 7 * C, cnt, tmp, Nu);
    ln_relu_kernel<<<lnb_u, 256, 0, stream>>>(tmp, out_u, ln_g + 2 * C, ln_b + 2 * C, Nu);
}

// Round 3
// 2484.011 us; speedup vs baseline: 11.5616x; 11.5616x over previous
//
#include <hip/hip_runtime.h>

// HeteroGNN (2-layer bipartite SAGE-Hybrid).
// CSR gather-reduce aggregation (no atomic feature scatter) ->
// single split-bf16 MFMA GEMM with K-concat A' = [s | s/deg | x] (K=1536)
// against pre-stacked hi/lo bf16 B' -> LN+ReLU.
// out = s@Wl0^T + (s/max(deg,1))@Wl1^T + x_dst@(Wr0+Wr1)^T + (bl0+bl1)

typedef float f4 __attribute__((ext_vector_type(4)));
typedef short short8 __attribute__((ext_vector_type(8)));

#define C 512
#define CC (512*512)
#define NST 48          // K-steps: 1536 / 32
#define BSTEP 16384     // 512*32 elements per (step,plane) B panel

// fp32 -> (hi, lo) bf16 split, both RNE. x == hi + lo up to ~2^-17 rel.
__device__ __forceinline__ void bf16split(float x, short& h, short& l) {
    unsigned u = __float_as_uint(x);
    unsigned hb = (u + 0x7FFFu + ((u >> 16) & 1u)) & 0xFFFF0000u;
    h = (short)(hb >> 16);
    float r = x - __uint_as_float(hb);
    unsigned ur = __float_as_uint(r);
    l = (short)((ur + 0x7FFFu + ((ur >> 16) & 1u)) >> 16);
}

// ---------------- weight prep (unchanged) ----------------
__global__ __launch_bounds__(256) void prep_b_kernel(
    const float* __restrict__ Wl, const float* __restrict__ Wr,
    unsigned short* __restrict__ Bp)
{
    int nrow = blockIdx.x;                  // output col n (0..511)
    int z = blockIdx.y;                     // d*3 + j
    int d = z / 3, j = z - d * 3;
    const float* s0 = (j < 2) ? Wl + (size_t)(d * 2 + j) * CC
                              : Wr + (size_t)(d * 2 + 0) * CC;
    const float* s1 = (j == 2) ? Wr + (size_t)(d * 2 + 1) * CC : nullptr;
    int t = threadIdx.x;
    #pragma unroll
    for (int c = 0; c < 2; ++c) {
        int kk = t + c * 256;               // source k (0..511), coalesced
        float v = s0[(size_t)nrow * C + kk];
        if (s1) v += s1[(size_t)nrow * C + kk];
        short hh, ll;
        bf16split(v, hh, ll);
        int st = 3 * (kk >> 5) + j;
        int k = kk & 31;
        size_t base = (size_t)(d * NST + st) * 2 * BSTEP + (size_t)nrow * 32 + k;
        Bp[base] = (unsigned short)hh;
        Bp[base + BSTEP] = (unsigned short)ll;
    }
}

// ---------------- CSR build ----------------
__global__ __launch_bounds__(256) void count_kernel(
    const int* __restrict__ dst, int* __restrict__ deg, int E)
{
    int i = blockIdx.x * 256 + threadIdx.x;
    if (i < E) atomicAdd(&deg[dst[i]], 1);
}

// single-block exclusive scan of deg[0..N) -> row_ptr[0..N], cursor copy
__global__ __launch_bounds__(1024) void scan_kernel(
    const int* __restrict__ deg, int* __restrict__ row_ptr,
    int* __restrict__ cursor, int N)
{
    __shared__ int part[1024];
    int t = threadIdx.x;
    int chunk = (N + 1023) / 1024;
    int b = t * chunk, e = b + chunk; if (e > N) e = N; if (b > N) b = N;
    int s = 0;
    for (int i = b; i < e; ++i) s += deg[i];
    part[t] = s;
    __syncthreads();
    for (int off = 1; off < 1024; off <<= 1) {
        int v = (t >= off) ? part[t - off] : 0;
        __syncthreads();
        part[t] += v;
        __syncthreads();
    }
    int base = (t == 0) ? 0 : part[t - 1];
    for (int i = b; i < e; ++i) {
        int d = deg[i];
        row_ptr[i] = base; cursor[i] = base;
        base += d;
    }
    if (t == 0) row_ptr[N] = part[1023];
}

__global__ __launch_bounds__(256) void fill_kernel(
    const int* __restrict__ src, const int* __restrict__ dst,
    int* __restrict__ cursor, int* __restrict__ se, int E)
{
    int i = blockIdx.x * 256 + threadIdx.x;
    if (i < E) {
        int pos = atomicAdd(&cursor[dst[i]], 1);
        se[pos] = src[i];
    }
}

// ---------------- aggregation: S[r] = sum_{e in CSR[r]} X[se[e]] ----------------
// one wave per dst row; lane holds 8 consecutive floats in regs.
__global__ __launch_bounds__(256) void agg_kernel(
    const float* __restrict__ X, const int* __restrict__ row_ptr,
    const int* __restrict__ se, float* __restrict__ S, int N)
{
    int r = blockIdx.x * 4 + (threadIdx.x >> 6);
    if (r >= N) return;
    int lane = threadIdx.x & 63;
    int beg = row_ptr[r], end = row_ptr[r + 1];
    f4 a0 = (f4)0.0f, a1 = (f4)0.0f;
    for (int e = beg; e < end; ++e) {
        int si = se[e];
        const f4* xp = (const f4*)(X + (size_t)si * C) + lane * 2;
        a0 += xp[0];
        a1 += xp[1];
    }
    float* sp = S + (size_t)r * C + lane * 8;
    *(f4*)sp = a0;
    *(f4*)(sp + 4) = a1;
}

// ---------------- split-bf16 MFMA GEMM ----------------
// Out[r][n] = sum_k' A'[r][k'] B'[k'][n] + bias0[n] + bias1[n]
// A' staged per 32-step from global fp32 (s / s*ic / x per step%3), split to
// hi/lo bf16 in LDS. Tile 128x128, 4 waves (2x2), wave tile 64x64 (4x4 frags
// of 16x16), mfma_f32_16x16x32_bf16, 3 products per frag-step (drop lo*lo).
__global__ __launch_bounds__(256) void gemm_mfma_kernel(
    const float* __restrict__ S, const float* __restrict__ Xd,
    const unsigned short* __restrict__ BpD,     // this direction's panels
    const float* __restrict__ bias0, const float* __restrict__ bias1,
    const int* __restrict__ rp, float* __restrict__ Out, int n)
{
    __shared__ __align__(16) unsigned short Ah[128][40];
    __shared__ __align__(16) unsigned short Al[128][40];
    __shared__ __align__(16) unsigned short Bh[128][40];
    __shared__ __align__(16) unsigned short Bl[128][40];

    int t = threadIdx.x;
    int row0 = blockIdx.x * 128, col0 = blockIdx.y * 128;
    int wid = t >> 6, l = t & 63;
    int wm = wid >> 1, wn = wid & 1;
    int ln = l & 15, kg = l >> 4;

    // A staging: thread t -> row ar, k-half akh (16 of 32)
    int ar = t >> 1, akh = (t & 1) * 16;
    int rc = row0 + ar; if (rc > n - 1) rc = n - 1;       // clamp (invalid rows harmless)
    int degr = rp[rc + 1] - rp[rc];
    float ic = 1.0f / (float)(degr > 1 ? degr : 1);
    const float* Sp = S + (size_t)rc * C;
    const float* Xp = Xd + (size_t)rc * C;
    // B staging: thread t -> local col t>>2 (+64), k-offset (t&3)*8
    int bnr = t >> 2, bko = (t & 3) * 8;

    f4 acc[4][4];
    #pragma unroll
    for (int i = 0; i < 4; ++i)
        #pragma unroll
        for (int jj = 0; jj < 4; ++jj) acc[i][jj] = (f4)0.0f;

    f4 pa[4];
    short8 pb0[2], pb1[2];
    int gcur;

    // prologue: load step 0
    {
        const float* ab = Sp + akh;           // st=0 -> kt=0, g=0 -> S
        pa[0] = *(const f4*)ab; pa[1] = *(const f4*)(ab + 4);
        pa[2] = *(const f4*)(ab + 8); pa[3] = *(const f4*)(ab + 12);
        const unsigned short* bp = BpD + (size_t)(col0 + bnr) * 32 + bko;
        pb0[0] = *(const short8*)bp;
        pb0[1] = *(const short8*)(bp + 64 * 32);
        pb1[0] = *(const short8*)(bp + BSTEP);
        pb1[1] = *(const short8*)(bp + BSTEP + 64 * 32);
        gcur = 0;
    }

    for (int st = 0; st < NST; ++st) {
        __syncthreads();
        // ---- write staged regs to LDS (split A to hi/lo) ----
        {
            float sc = (gcur == 1) ? ic : 1.0f;
            short8 h0, l0, h1, l1;
            #pragma unroll
            for (int q = 0; q < 2; ++q)
                #pragma unroll
                for (int jj = 0; jj < 4; ++jj) {
                    short hh, ll;
                    bf16split(pa[q][jj] * sc, hh, ll);
                    h0[q * 4 + jj] = hh; l0[q * 4 + jj] = ll;
                }
            #pragma unroll
            for (int q = 0; q < 2; ++q)
                #pragma unroll
                for (int jj = 0; jj < 4; ++jj) {
                    short hh, ll;
                    bf16split(pa[q + 2][jj] * sc, hh, ll);
                    h1[q * 4 + jj] = hh; l1[q * 4 + jj] = ll;
                }
            *(short8*)&Ah[ar][akh] = h0; *(short8*)&Ah[ar][akh + 8] = h1;
            *(short8*)&Al[ar][akh] = l0; *(short8*)&Al[ar][akh + 8] = l1;
            *(short8*)&Bh[bnr][bko] = pb0[0]; *(short8*)&Bh[bnr + 64][bko] = pb0[1];
            *(short8*)&Bl[bnr][bko] = pb1[0]; *(short8*)&Bl[bnr + 64][bko] = pb1[1];
        }
        __syncthreads();
        // ---- prefetch step st+1 into regs (overlaps with MFMAs below) ----
        if (st + 1 < NST) {
            int stn = st + 1;
            int kt = stn / 3, g = stn - kt * 3;
            const float* ab = (g == 2 ? Xp : Sp) + kt * 32 + akh;
            pa[0] = *(const f4*)ab; pa[1] = *(const f4*)(ab + 4);
            pa[2] = *(const f4*)(ab + 8); pa[3] = *(const f4*)(ab + 12);
            const unsigned short* bp = BpD + (size_t)(stn * 2) * BSTEP
                                     + (size_t)(col0 + bnr) * 32 + bko;
            pb0[0] = *(const short8*)bp;
            pb0[1] = *(const short8*)(bp + 64 * 32);
            pb1[0] = *(const short8*)(bp + BSTEP);
            pb1[1] = *(const short8*)(bp + BSTEP + 64 * 32);
            gcur = g;
        }
        // ---- compute: 16 frags x 3 split-products ----
        {
            short8 fbh[4], fbl[4];
            #pragma unroll
            for (int nf = 0; nf < 4; ++nf) {
                fbh[nf] = *(const short8*)&Bh[wn * 64 + nf * 16 + ln][kg * 8];
                fbl[nf] = *(const short8*)&Bl[wn * 64 + nf * 16 + ln][kg * 8];
            }
            #pragma unroll
            for (int mf = 0; mf < 4; ++mf) {
                short8 fah = *(const short8*)&Ah[wm * 64 + mf * 16 + ln][kg * 8];
                short8 fal = *(const short8*)&Al[wm * 64 + mf * 16 + ln][kg * 8];
                #pragma unroll
                for (int nf = 0; nf < 4; ++nf) {
                    acc[mf][nf] = __builtin_amdgcn_mfma_f32_16x16x32_bf16(
                        fah, fbh[nf], acc[mf][nf], 0, 0, 0);
                    acc[mf][nf] = __builtin_amdgcn_mfma_f32_16x16x32_bf16(
                        fah, fbl[nf], acc[mf][nf], 0, 0, 0);
                    acc[mf][nf] = __builtin_amdgcn_mfma_f32_16x16x32_bf16(
                        fal, fbh[nf], acc[mf][nf], 0, 0, 0);
                }
            }
        }
    }

    // ---- epilogue: bias + store (C/D: col = lane&15, row = (lane>>4)*4+reg) ----
    float bv[4];
    #pragma unroll
    for (int nf = 0; nf < 4; ++nf) {
        int cc = col0 + wn * 64 + nf * 16 + ln;
        bv[nf] = bias0[cc] + bias1[cc];
    }
    #pragma unroll
    for (int mf = 0; mf < 4; ++mf) {
        int rbase = row0 + wm * 64 + mf * 16 + kg * 4;
        #pragma unroll
        for (int jj = 0; jj < 4; ++jj) {
            int row = rbase + jj;
            if (row < n) {
                #pragma unroll
                for (int nf = 0; nf < 4; ++nf)
                    Out[(size_t)row * C + col0 + wn * 64 + nf * 16 + ln] =
                        acc[mf][nf][jj] + bv[nf];
            }
        }
    }
}

// ---------------- LayerNorm + ReLU (wave per row, matches jnp.var) ----------------
__global__ __launch_bounds__(256) void ln_relu_kernel(
    const float* __restrict__ In, float* __restrict__ Out,
    const float* __restrict__ g, const float* __restrict__ b, int N)
{
    int row = blockIdx.x * 4 + (threadIdx.x >> 6);
    if (row >= N) return;
    int lane = threadIdx.x & 63;
    const float* ip = In + (size_t)row * C + lane * 8;
    f4 v0 = *(const f4*)ip;
    f4 v1 = *(const f4*)(ip + 4);
    float s = v0[0] + v0[1] + v0[2] + v0[3] + v1[0] + v1[1] + v1[2] + v1[3];
    #pragma unroll
    for (int off = 32; off > 0; off >>= 1) s += __shfl_xor(s, off, 64);
    float mu = s * (1.0f / 512.0f);
    f4 e0 = v0 - mu, e1 = v1 - mu;
    float q = e0[0]*e0[0] + e0[1]*e0[1] + e0[2]*e0[2] + e0[3]*e0[3]
            + e1[0]*e1[0] + e1[1]*e1[1] + e1[2]*e1[2] + e1[3]*e1[3];
    #pragma unroll
    for (int off = 32; off > 0; off >>= 1) q += __shfl_xor(q, off, 64);
    float rs = rsqrtf(q * (1.0f / 512.0f) + 1e-5f);
    const float* gp = g + lane * 8;
    const float* bp = b + lane * 8;
    f4 g0 = *(const f4*)gp, g1 = *(const f4*)(gp + 4);
    f4 bb0 = *(const f4*)bp, bb1 = *(const f4*)(bp + 4);
    f4 o0 = g0 * (e0 * rs) + bb0;
    f4 o1 = g1 * (e1 * rs) + bb1;
    #pragma unroll
    for (int jj = 0; jj < 4; ++jj) { o0[jj] = fmaxf(o0[jj], 0.0f); o1[jj] = fmaxf(o1[jj], 0.0f); }
    float* op = Out + (size_t)row * C + lane * 8;
    *(f4*)op = o0;
    *(f4*)(op + 4) = o1;
}

extern "C" void kernel_launch(void* const* d_in, const int* in_sizes, int n_in,
                              void* d_out, int out_size, void* d_ws, size_t ws_size,
                              hipStream_t stream)
{
    (void)n_in; (void)out_size; (void)ws_size;
    const float* x_user = (const float*)d_in[0];
    const float* x_item = (const float*)d_in[1];
    const float* Wl     = (const float*)d_in[2];
    const float* bl     = (const float*)d_in[3];
    const float* Wr     = (const float*)d_in[4];
    const float* ln_g   = (const float*)d_in[5];
    const float* ln_b   = (const float*)d_in[6];
    const int* edge_ui  = (const int*)d_in[7];
    const int* edge_iu  = (const int*)d_in[8];

    int Nu = in_sizes[0] / C;
    int Ni = in_sizes[1] / C;
    int E  = in_sizes[7] / 2;
    int Nmax = Nu > Ni ? Nu : Ni;

    float* out_u = (float*)d_out;
    float* out_i = out_u + (size_t)Nu * C;

    // ws layout:
    //   Bp    : 4*NST*2*BSTEP ushort (12.6 MB)
    //   sbuf  : Nmax*C f32 (102.4 MB)   -- aggregation sums
    //   tmp   : Nmax*C f32 (102.4 MB)   -- layer-2 GEMM staging
    //   rp_i  : Ni+1 ints ; rp_u : Nu+1 ints
    //   cur_i : Ni ints   ; cur_u: Nu ints
    //   deg_i : Ni ints   ; deg_u: Nu ints   (contiguous pair -> one memset)
    //   se_i  : E ints    ; se_u : E ints
    unsigned short* Bp = (unsigned short*)d_ws;
    float* sbuf = (float*)(Bp + (size_t)4 * NST * 2 * BSTEP);
    float* tmp  = sbuf + (size_t)Nmax * C;
    int* rp_i   = (int*)(tmp + (size_t)Nmax * C);
    int* rp_u   = rp_i + (Ni + 1);
    int* cur_i  = rp_u + (Nu + 1);
    int* cur_u  = cur_i + Ni;
    int* deg_i  = cur_u + Nu;
    int* deg_u  = deg_i + Ni;
    int* se_i   = deg_u + Nu;
    int* se_u   = se_i + E;

    size_t dstride = (size_t)NST * 2 * BSTEP;   // Bp per-direction stride
    int gE = (E + 255) / 256;

    // -------- one-time prep: B panels + CSR for both directions --------
    prep_b_kernel<<<dim3(512, 12), 256, 0, stream>>>(Wl, Wr, Bp);
    hipMemsetAsync(deg_i, 0, (size_t)(Ni + Nu) * sizeof(int), stream);
    count_kernel<<<gE, 256, 0, stream>>>(edge_ui + E, deg_i, E);
    count_kernel<<<gE, 256, 0, stream>>>(edge_iu + E, deg_u, E);
    scan_kernel<<<1, 1024, 0, stream>>>(deg_i, rp_i, cur_i, Ni);
    scan_kernel<<<1, 1024, 0, stream>>>(deg_u, rp_u, cur_u, Nu);
    fill_kernel<<<gE, 256, 0, stream>>>(edge_ui, edge_ui + E, cur_i, se_i, E);
    fill_kernel<<<gE, 256, 0, stream>>>(edge_iu, edge_iu + E, cur_u, se_u, E);

    dim3 ggemm_i((Ni + 127) / 128, 4), ggemm_u((Nu + 127) / 128, 4);
    int gagg_i = (Ni + 3) / 4, gagg_u = (Nu + 3) / 4;
    int lnb_i = (Ni + 3) / 4, lnb_u = (Nu + 3) / 4;

    // -------- layer 1 (reads pristine inputs, writes d_out, LN in-place) --------
    agg_kernel<<<gagg_i, 256, 0, stream>>>(x_user, rp_i, se_i, sbuf, Ni);
    gemm_mfma_kernel<<<ggemm_i, 256, 0, stream>>>(sbuf, x_item, Bp + 0 * dstride,
                                                  bl + 0 * C, bl + 1 * C, rp_i, out_i, Ni);
    agg_kernel<<<gagg_u, 256, 0, stream>>>(x_item, rp_u, se_u, sbuf, Nu);
    gemm_mfma_kernel<<<ggemm_u, 256, 0, stream>>>(sbuf, x_user, Bp + 1 * dstride,
                                                  bl + 2 * C, bl + 3 * C, rp_u, out_u, Nu);
    ln_relu_kernel<<<lnb_u, 256, 0, stream>>>(out_u, out_u, ln_g + 0 * C, ln_b + 0 * C, Nu);
    ln_relu_kernel<<<lnb_i, 256, 0, stream>>>(out_i, out_i, ln_g + 1 * C, ln_b + 1 * C, Ni);

    // -------- layer 2 (single tmp buffer via ordering) --------
    agg_kernel<<<gagg_i, 256, 0, stream>>>(out_u, rp_i, se_i, sbuf, Ni);
    gemm_mfma_kernel<<<ggemm_i, 256, 0, stream>>>(sbuf, out_i, Bp + 2 * dstride,
                                                  bl + 4 * C, bl + 5 * C, rp_i, tmp, Ni);
    agg_kernel<<<gagg_u, 256, 0, stream>>>(out_i, rp_u, se_u, sbuf, Nu);   // old xi still intact
    ln_relu_kernel<<<lnb_i, 256, 0, stream>>>(tmp, out_i, ln_g + 3 * C, ln_b + 3 * C, Ni);
    gemm_mfma_kernel<<<ggemm_u, 256, 0, stream>>>(sbuf, out_u, Bp + 3 * dstride,
                                                  bl + 6 * C, bl + 7 * C, rp_u, tmp, Nu);
    ln_relu_kernel<<<lnb_u, 256, 0, stream>>>(tmp, out_u, ln_g + 2 * C, ln_b + 2 * C, Nu);
}